// Round 14
// baseline (129.409 us; speedup 1.0000x reference)
//
#include <hip/hip_runtime.h>
#include <math.h>

#define VV 8192
#define DD 768
#define NDMAX 256

typedef __attribute__((ext_vector_type(8))) short bf16x8;
typedef __attribute__((ext_vector_type(4))) float f32x4;

// RNE float -> bf16 bits
__device__ inline ushort f2bf(float f) {
    uint u = __float_as_uint(f);
    uint r = (u + 0x7fffu + ((u >> 16) & 1u)) >> 16;
    return (ushort)r;
}
__device__ inline float bf2f(ushort h) { return __uint_as_float(((uint)h) << 16); }

__device__ inline void gload16(const ushort* g, ushort* l) {
    __builtin_amdgcn_global_load_lds(
        (const __attribute__((address_space(1))) void*)g,
        (__attribute__((address_space(3))) void*)l, 16, 0, 0);
}

// ---------------------------------------------------------------------------
// k_normfused: per row -- L2-normalize (fp64 sumsq) -> xh/xl bf16 hi/lo
// split + norms[r]; PLUS fused column-sum partials of x = fp32(t/norm) in
// fp64. 512 blocks x 16 rows, 2-row ILP. Zeroes rc, dlist, dcount.
// ---------------------------------------------------------------------------
__global__ __launch_bounds__(256) void k_normfused(const float* __restrict__ t,
                                                   float* __restrict__ norms,
                                                   ushort* __restrict__ xh,
                                                   ushort* __restrict__ xl,
                                                   double* __restrict__ gp,
                                                   float* __restrict__ rc,
                                                   int* __restrict__ dlist,
                                                   int* __restrict__ dcount) {
    const int tid = threadIdx.x;
    const int r0 = blockIdx.x * 16;
    if (tid < 16) rc[r0 + tid] = 0.f;
    if (blockIdx.x == 0) {
        dlist[tid] = -1;
        if (tid == 0) *dcount = 0;
    }
    __shared__ double wsum[2][4];
    const int lane = tid & 63, w = tid >> 6;
    double s0 = 0.0, s1 = 0.0, s2 = 0.0;
    for (int rr = 0; rr < 16; rr += 2) {
        const float* trA = t + (size_t)(r0 + rr) * DD;
        const float* trB = trA + DD;
        float a0 = trA[tid], a1 = trA[tid + 256], a2 = trA[tid + 512];
        float b0 = trB[tid], b1 = trB[tid + 256], b2 = trB[tid + 512];
        double sA = (double)a0 * a0 + (double)a1 * a1 + (double)a2 * a2;
        double sB = (double)b0 * b0 + (double)b1 * b1 + (double)b2 * b2;
#pragma unroll
        for (int o = 32; o > 0; o >>= 1) {
            sA += __shfl_down(sA, o, 64);
            sB += __shfl_down(sB, o, 64);
        }
        if (lane == 0) { wsum[0][w] = sA; wsum[1][w] = sB; }
        __syncthreads();
        float nA = fmaxf((float)sqrt(wsum[0][0] + wsum[0][1] + wsum[0][2] + wsum[0][3]), 1e-12f);
        float nB = fmaxf((float)sqrt(wsum[1][0] + wsum[1][1] + wsum[1][2] + wsum[1][3]), 1e-12f);
        __syncthreads();  // wsum reuse protection
        if (tid == 0) {
            norms[r0 + rr] = nA;
            norms[r0 + rr + 1] = nB;
        }
        size_t baseA = (size_t)(r0 + rr) * DD, baseB = baseA + DD;
        float xA0 = a0 / nA, xA1 = a1 / nA, xA2 = a2 / nA;
        float xB0 = b0 / nB, xB1 = b1 / nB, xB2 = b2 / nB;
        ushort h;
        h = f2bf(xA0); xh[baseA + tid] = h;       xl[baseA + tid] = f2bf(xA0 - bf2f(h));
        h = f2bf(xA1); xh[baseA + tid + 256] = h; xl[baseA + tid + 256] = f2bf(xA1 - bf2f(h));
        h = f2bf(xA2); xh[baseA + tid + 512] = h; xl[baseA + tid + 512] = f2bf(xA2 - bf2f(h));
        h = f2bf(xB0); xh[baseB + tid] = h;       xl[baseB + tid] = f2bf(xB0 - bf2f(h));
        h = f2bf(xB1); xh[baseB + tid + 256] = h; xl[baseB + tid + 256] = f2bf(xB1 - bf2f(h));
        h = f2bf(xB2); xh[baseB + tid + 512] = h; xl[baseB + tid + 512] = f2bf(xB2 - bf2f(h));
        s0 += (double)xA0; s0 += (double)xB0;
        s1 += (double)xA1; s1 += (double)xB1;
        s2 += (double)xA2; s2 += (double)xB2;
    }
    double* gb = gp + (size_t)blockIdx.x * DD;
    gb[tid] = s0;
    gb[tid + 256] = s1;
    gb[tid + 512] = s2;
}

// ---------------------------------------------------------------------------
// k_colsumB: g[col] = sum of 512 block partials in fixed order (fp64,
// deterministic, atomic-free).
// ---------------------------------------------------------------------------
__global__ __launch_bounds__(256) void k_colsumB(const double* __restrict__ gp,
                                                 double* __restrict__ g) {
    __shared__ double red[8][32];
    int c = threadIdx.x & 31, part = threadIdx.x >> 5;
    int col = blockIdx.x * 32 + c;
    double s = 0.0;
    for (int b = part * 64; b < part * 64 + 64; ++b)
        s += gp[(size_t)b * DD + col];
    red[part][c] = s;
    __syncthreads();
    if (part == 0) {
        double tt = 0.0;
        for (int p = 0; p < 8; ++p) tt += red[p][c];
        g[col] = tt;
    }
}

// ---------------------------------------------------------------------------
// k_mean: mnum[r] = x_r.g - x_r.x_r (fp64); dd[r] = x_r.x_r. Exact mean
// path -- numerically deadly, do not approximate. Danger-row selection
// fused (atomic compaction; slot order irrelevant).
// ---------------------------------------------------------------------------
__global__ __launch_bounds__(256) void k_mean(const float* __restrict__ t,
                                              const float* __restrict__ norms,
                                              const double* __restrict__ g,
                                              double* __restrict__ mnum,
                                              double* __restrict__ dd,
                                              int* __restrict__ dlist,
                                              int* __restrict__ dcount) {
    int r = blockIdx.x * 4 + (threadIdx.x >> 6);
    int lane = threadIdx.x & 63;
    const float* tr = t + (size_t)r * DD;
    float nrm = norms[r];
    double xg = 0.0, xx = 0.0;
#pragma unroll
    for (int k = lane; k < DD; k += 64) {
        float xf = tr[k] / nrm;
        double xv = (double)xf;
        xg += xv * g[k];
        xx += xv * xv;
    }
#pragma unroll
    for (int o = 32; o > 0; o >>= 1) {
        xg += __shfl_down(xg, o, 64);
        xx += __shfl_down(xx, o, 64);
    }
    if (lane == 0) {
        double m = xg - xx;
        mnum[r] = m;
        dd[r] = xx;
        if (fabs(m / 8191.0 + 1e-6) < 1e-5) {
            int pos = atomicAdd(dcount, 1);
            if (pos < NDMAX) dlist[pos] = r;
        }
    }
}

// ---------------------------------------------------------------------------
// cube_loop<NLB>: the shared K=768 MFMA loop (24 steps, BK=32, triple-
// buffered, prefetch distance 2, counted vmcnt + raw s_barrier). NLB = B
// gloads per thread (4 -> 256-col tile, NB=8 frags; 2 -> 128-col, NB=4).
// Per-step loads = 2+NLB; vmcnt(2+NLB) = "previous step's loads landed,
// newest step stays in flight" (issued 2 full steps before the wait).
// ---------------------------------------------------------------------------
template <int NLB>
__device__ __forceinline__ void cube_loop(
    const ushort* __restrict__ XA, const ushort* __restrict__ XB,
    int asrc0, int asrc1, int bsrc0, int bsrc1, int bsrc2, int bsrc3,
    int lda0, int lda1, int ldb0, int ldb1, int ldb2, int ldb3,
    int aoff, int boff,
    ushort* As0, ushort* As1, ushort* As2,
    ushort* Bs0, ushort* Bs1, ushort* Bs2,
    f32x4 (&acc)[4][8]) {
    constexpr int NB = 2 * NLB;

#define STG(AW, BW, KT)                                                  \
    do {                                                                 \
        const int kq_ = (KT) * 32;                                       \
        gload16(XA + asrc0 + kq_, (AW) + lda0);                          \
        gload16(XA + asrc1 + kq_, (AW) + lda1);                          \
        gload16(XB + bsrc0 + kq_, (BW) + ldb0);                          \
        gload16(XB + bsrc1 + kq_, (BW) + ldb1);                          \
        if constexpr (NLB == 4) {                                        \
            gload16(XB + bsrc2 + kq_, (BW) + ldb2);                      \
            gload16(XB + bsrc3 + kq_, (BW) + ldb3);                      \
        }                                                                \
    } while (0)

#define COMPUTE(AR, BR)                                                     \
    do {                                                                    \
        bf16x8 av[4], bv[NB];                                               \
        _Pragma("unroll") for (int f = 0; f < 4; ++f)                       \
            av[f] = *(const bf16x8*)((AR) + aoff + f * 512);                \
        _Pragma("unroll") for (int n = 0; n < NB; ++n)                      \
            bv[n] = *(const bf16x8*)((BR) + boff + n * 512);                \
        _Pragma("unroll") for (int f = 0; f < 4; ++f)                       \
            _Pragma("unroll") for (int n = 0; n < NB; ++n)                  \
                acc[f][n] = __builtin_amdgcn_mfma_f32_16x16x32_bf16(        \
                    av[f], bv[n], acc[f][n], 0, 0, 0);                      \
    } while (0)

#define VMWP()                                                           \
    do {                                                                 \
        if constexpr (NLB == 4)                                          \
            asm volatile("s_waitcnt vmcnt(6)" ::: "memory");              \
        else                                                             \
            asm volatile("s_waitcnt vmcnt(4)" ::: "memory");              \
    } while (0)
#define VMW0() asm volatile("s_waitcnt vmcnt(0)" ::: "memory")
#define RBAR() asm volatile("s_barrier" ::: "memory")

    // prologue: stage steps 0 and 1
    STG(As0, Bs0, 0);
    STG(As1, Bs1, 1);
    VMWP(); RBAR();  // step-0 loads landed

    for (int tb = 0; tb < 21; tb += 3) {
        STG(As2, Bs2, tb + 2);
        COMPUTE(As0, Bs0);
        VMWP(); RBAR();
        STG(As0, Bs0, tb + 3);
        COMPUTE(As1, Bs1);
        VMWP(); RBAR();
        STG(As1, Bs1, tb + 4);
        COMPUTE(As2, Bs2);
        VMWP(); RBAR();
    }
    STG(As2, Bs2, 23);
    COMPUTE(As0, Bs0);
    VMWP(); RBAR();
    COMPUTE(As1, Bs1);
    VMW0(); RBAR();
    COMPUTE(As2, Bs2);
#undef STG
#undef COMPUTE
#undef VMWP
#undef VMW0
#undef RBAR
}

// ---------------------------------------------------------------------------
// k_cube: bf16 MFMA pass with mixed-size tail-fill (kills the 2.44->3-round
// quantization tail: 192 strips + 832 full tiles = exactly 2 rounds at
// 2 blocks/CU, then 448 half-tiles (~0.6 length) pack the final ~0.65 round).
//  - bids 0..191: strip-partial (3 seg x 2 rowpanel x 32 colchunk): danger
//    rows (gathered) x 256 cols -> store partial S into Sb (no cube);
//    empty-rowpanel early-exit.
//  - bids 192..1023: full triangle tiles 128x256 (hh only) -- j-major
//    positions 0..103 of each of 8 XCD chunks (132 each).
//  - bids 1024..1471: HALF tiles 128x128, full K -- the last 28 positions
//    of each chunk, two halves (h=0,1) per tile, dispatched last.
//  dtile (bi>>1==bj): row-side only + ri==cj skip (in-block pairs covered
//  exactly once); strictly-upper: row + col sides via symmetry.
// Inner loop: see cube_loop -- at the m97-verified plateau (~860 TF
// in-flight), left untouched.
// ---------------------------------------------------------------------------
__global__ __launch_bounds__(256, 2) void k_cube(const ushort* __restrict__ xh,
                                                 const ushort* __restrict__ xl,
                                                 const int* __restrict__ dlist,
                                                 float* __restrict__ Sb,
                                                 float* __restrict__ rc) {
    __shared__ ushort As0[4096], As1[4096], As2[4096];  // 128x32 bf16 each
    __shared__ ushort Bs0[8192], Bs1[8192], Bs2[8192];  // 256x32 bf16 each

    const int bid = blockIdx.x;
    const int tid = threadIdx.x;
    const int lane = tid & 63;
    const int wid = tid >> 6;
    const int l15 = lane & 15, li4 = lane >> 4;
    const int wm = wid >> 1, wn = wid & 1;

    const bool strip = (bid < 192);
    const bool half = (bid >= 1024);
    int bi = 0, bj = 0, seg = 0, rp = 0, cp = 0, hh = 0;
    if (strip) {
        seg = bid >> 6;
        int rem = bid & 63;
        rp = rem >> 5;
        cp = rem & 31;
        if (dlist[rp * 128] < 0) return;  // empty rowpanel (contiguous fill)
    } else {
        int wg;
        if (!half) {
            int idx = bid - 192;                     // 0..831
            wg = (idx & 7) * 132 + (idx >> 3);       // chunk positions 0..103
        } else {
            int hx = bid - 1024;                     // 0..447
            int q = hx >> 1;                         // tile 0..223
            hh = hx & 1;
            wg = (q & 7) * 132 + 104 + (q >> 3);     // chunk positions 104..131
        }
        int j = 0;
        while (wg >= 2 * j + 2) { wg -= 2 * j + 2; ++j; }  // j-major, i inner
        bi = wg;   // 0..2j+1
        bj = j;
    }
    const ushort* XA = strip ? ((seg == 1) ? xl : xh) : xh;
    const ushort* XB = strip ? ((seg == 2) ? xl : xh) : xh;

    // staging descriptors: A 2 gloads/thread; B 4 (full/strip) or 2 (half)
    int asrc[2], bsrc[4] = {0, 0, 0, 0}, lda_[2], ldb_[4] = {0, 0, 0, 0};
#pragma unroll
    for (int j = 0; j < 2; ++j) {
        int li = tid + j * 256;                    // 0..511
        int row = li >> 2;                         // 0..127
        int sl = ((li & 3) ^ ((li >> 3) & 3)) * 8; // pre-swizzled source slot
        int ar = strip ? dlist[rp * 128 + row] : (bi * 128 + row);
        if (ar < 0) ar = 0;
        asrc[j] = ar * DD + sl;
        lda_[j] = li * 8;
    }
    const int nbl = half ? 2 : 4;
    for (int j = 0; j < nbl; ++j) {
        int li = tid + j * 256;                    // rows 0..255 (or 0..127)
        int row = li >> 2;
        int sl = ((li & 3) ^ ((li >> 3) & 3)) * 8;
        int br = strip ? (cp * 256 + row)
                       : (bj * 256 + (half ? hh * 128 : 0) + row);
        bsrc[j] = br * DD + sl;
        ldb_[j] = li * 8;
    }

    const int swz = (li4 ^ ((l15 >> 1) & 3)) << 3;
    const int aoff = (wm * 64 + l15) * 32 + swz;
    const int boff = ((wn * (half ? 64 : 128)) + l15) * 32 + swz;

    f32x4 acc[4][8];
#pragma unroll
    for (int f = 0; f < 4; ++f)
#pragma unroll
        for (int n = 0; n < 8; ++n) acc[f][n] = (f32x4){0.f, 0.f, 0.f, 0.f};

    if (half) {
        cube_loop<2>(XA, XB, asrc[0], asrc[1], bsrc[0], bsrc[1], bsrc[2], bsrc[3],
                     lda_[0], lda_[1], ldb_[0], ldb_[1], ldb_[2], ldb_[3],
                     aoff, boff, As0, As1, As2, Bs0, Bs1, Bs2, acc);
        // half epilogue: 128 cols (4 n-frags)
        const bool dtile = ((bi >> 1) == bj);
        const int R0 = bi * 128, C0 = bj * 256 + hh * 128;
        float rsum[4][4], csum[4];
#pragma unroll
        for (int n = 0; n < 4; ++n) csum[n] = 0.f;
#pragma unroll
        for (int f = 0; f < 4; ++f)
#pragma unroll
            for (int r = 0; r < 4; ++r) rsum[f][r] = 0.f;
#pragma unroll
        for (int f = 0; f < 4; ++f)
#pragma unroll
            for (int n = 0; n < 4; ++n)
#pragma unroll
                for (int r = 0; r < 4; ++r) {
                    float s = acc[f][n][r];
                    float c = s * s * s;
                    int ri = R0 + wm * 64 + f * 16 + li4 * 4 + r;
                    int cj = C0 + wn * 64 + n * 16 + l15;
                    if (dtile && ri == cj) c = 0.f;
                    rsum[f][r] += c;
                    csum[n] += c;
                }
#pragma unroll
        for (int o = 1; o < 16; o <<= 1)
#pragma unroll
            for (int f = 0; f < 4; ++f)
#pragma unroll
                for (int r = 0; r < 4; ++r)
                    rsum[f][r] += __shfl_xor(rsum[f][r], o, 64);
        if (l15 == 0) {
#pragma unroll
            for (int f = 0; f < 4; ++f)
#pragma unroll
                for (int r = 0; r < 4; ++r)
                    atomicAdd(&rc[R0 + wm * 64 + f * 16 + li4 * 4 + r], rsum[f][r]);
        }
        if (!dtile) {
#pragma unroll
            for (int o = 16; o < 64; o <<= 1)
#pragma unroll
                for (int n = 0; n < 4; ++n) csum[n] += __shfl_xor(csum[n], o, 64);
            if (li4 == 0) {
#pragma unroll
                for (int n = 0; n < 4; ++n)
                    atomicAdd(&rc[C0 + wn * 64 + n * 16 + l15], csum[n]);
            }
        }
        return;
    }

    cube_loop<4>(XA, XB, asrc[0], asrc[1], bsrc[0], bsrc[1], bsrc[2], bsrc[3],
                 lda_[0], lda_[1], ldb_[0], ldb_[1], ldb_[2], ldb_[3],
                 aoff, boff, As0, As1, As2, Bs0, Bs1, Bs2, acc);

    if (strip) {
        // store partial S (f32) by danger slot; finish pass cubes later
#pragma unroll
        for (int f = 0; f < 4; ++f)
#pragma unroll
            for (int n = 0; n < 8; ++n)
#pragma unroll
                for (int r = 0; r < 4; ++r) {
                    int slot = seg * 256 + rp * 128 + wm * 64 + f * 16 + li4 * 4 + r;
                    int col = cp * 256 + wn * 128 + n * 16 + l15;
                    Sb[((size_t)slot << 13) + col] = acc[f][n][r];
                }
        return;
    }

    // full-tile epilogue: cube; dtile: row-only with ri==cj skip;
    // strictly-upper: row + col (symmetry) sums.
    const bool dtile = ((bi >> 1) == bj);
    const int R0 = bi * 128, C0 = bj * 256;
    float rsum[4][4], csum[8];
#pragma unroll
    for (int n = 0; n < 8; ++n) csum[n] = 0.f;
#pragma unroll
    for (int f = 0; f < 4; ++f)
#pragma unroll
        for (int r = 0; r < 4; ++r) rsum[f][r] = 0.f;
#pragma unroll
    for (int f = 0; f < 4; ++f)
#pragma unroll
        for (int n = 0; n < 8; ++n)
#pragma unroll
            for (int r = 0; r < 4; ++r) {
                float s = acc[f][n][r];
                float c = s * s * s;
                int ri = R0 + wm * 64 + f * 16 + li4 * 4 + r;
                int cj = C0 + wn * 128 + n * 16 + l15;
                if (dtile && ri == cj) c = 0.f;
                rsum[f][r] += c;
                csum[n] += c;
            }
#pragma unroll
    for (int o = 1; o < 16; o <<= 1)
#pragma unroll
        for (int f = 0; f < 4; ++f)
#pragma unroll
            for (int r = 0; r < 4; ++r)
                rsum[f][r] += __shfl_xor(rsum[f][r], o, 64);
    if (l15 == 0) {
#pragma unroll
        for (int f = 0; f < 4; ++f)
#pragma unroll
            for (int r = 0; r < 4; ++r)
                atomicAdd(&rc[R0 + wm * 64 + f * 16 + li4 * 4 + r], rsum[f][r]);
    }
    if (!dtile) {
#pragma unroll
        for (int o = 16; o < 64; o <<= 1)
#pragma unroll
            for (int n = 0; n < 8; ++n) csum[n] += __shfl_xor(csum[n], o, 64);
        if (li4 == 0) {
#pragma unroll
            for (int n = 0; n < 8; ++n)
                atomicAdd(&rc[C0 + wn * 128 + n * 16 + l15], csum[n]);
        }
    }
}

// ---------------------------------------------------------------------------
// k_cubefin: per danger slot, correction = sum_c [(s0+s1+s2)^3 - s0^3]
// (skip c == drow; s0 bitwise-equals the triangle pass's hh value).
// ---------------------------------------------------------------------------
__global__ __launch_bounds__(256) void k_cubefin(const float* __restrict__ Sb,
                                                 const int* __restrict__ dlist,
                                                 float* __restrict__ rc) {
    const int slot = blockIdx.x;
    const int drow = dlist[slot];
    if (drow < 0) return;
    const int tid = threadIdx.x;
    const float* s0p = Sb + ((size_t)slot << 13);
    const float* s1p = Sb + ((size_t)(256 + slot) << 13);
    const float* s2p = Sb + ((size_t)(512 + slot) << 13);
    float sum = 0.f;
    for (int c = tid; c < VV; c += 256) {
        float s0 = s0p[c];
        float sf = s0 + s1p[c] + s2p[c];
        float d = sf * sf * sf - s0 * s0 * s0;
        if (c == drow) d = 0.f;
        sum += d;
    }
    __shared__ float red[256];
    red[tid] = sum;
    __syncthreads();
    for (int o = 128; o > 0; o >>= 1) {
        if (tid < o) red[tid] += red[tid + o];
        __syncthreads();
    }
    if (tid == 0) atomicAdd(&rc[drow], red[0]);
}

// ---------------------------------------------------------------------------
// k_final: out = collapse + 0.2 * sum_i rc_i / (mnum_i/8191 + 1e-6)
// ---------------------------------------------------------------------------
__global__ __launch_bounds__(1024) void k_final(const float* __restrict__ rc,
                                                const double* __restrict__ mnum,
                                                const double* __restrict__ dd,
                                                float* __restrict__ out) {
    int tid = threadIdx.x;
    double acc = 0.0, col = 0.0;
    for (int r = tid; r < VV; r += 1024) {
        double m = mnum[r] / 8191.0 + 1e-6;
        acc += (double)rc[r] / m;
        double dm = dd[r] - 1.0;
        col += dm * dm;
    }
    __shared__ double sa[1024], sc[1024];
    sa[tid] = acc;
    sc[tid] = col;
    __syncthreads();
    for (int o = 512; o > 0; o >>= 1) {
        if (tid < o) {
            sa[tid] += sa[tid + o];
            sc[tid] += sc[tid + o];
        }
        __syncthreads();
    }
    if (tid == 0) out[0] = (float)(sc[0] + 0.2 * sa[0]);
}

// ---------------------------------------------------------------------------
extern "C" void kernel_launch(void* const* d_in, const int* in_sizes, int n_in,
                              void* d_out, int out_size, void* d_ws, size_t ws_size,
                              hipStream_t stream) {
    const float* t = (const float*)d_in[0];
    float* out = (float*)d_out;

    char* ws = (char*)d_ws;
    float* Sb = (float*)ws;  // 3*256*8192*4B = 24 MB
    size_t off = (size_t)VV * DD * sizeof(float);  // keep 25.2 MB region
    ushort* xh = (ushort*)(ws + off); off += (size_t)VV * DD * sizeof(ushort);
    ushort* xl = (ushort*)(ws + off); off += (size_t)VV * DD * sizeof(ushort);
    double* g = (double*)(ws + off);  off += DD * sizeof(double);
    double* mnum = (double*)(ws + off); off += VV * sizeof(double);
    double* dd = (double*)(ws + off);  off += VV * sizeof(double);
    float* rc = (float*)(ws + off);    off += VV * sizeof(float);
    int* dlist = (int*)(ws + off);     off += NDMAX * sizeof(int);
    int* dcount = (int*)(ws + off);    off += sizeof(int) + 60;  // pad
    float* norms = (float*)(ws + off); off += VV * sizeof(float);
    double* gp = (double*)(ws + off);  off += (size_t)512 * DD * sizeof(double);

    k_normfused<<<512, 256, 0, stream>>>(t, norms, xh, xl, gp, rc, dlist, dcount);
    k_colsumB<<<24, 256, 0, stream>>>(gp, g);
    k_mean<<<VV / 4, 256, 0, stream>>>(t, norms, g, mnum, dd, dlist, dcount);
    k_cube<<<1472, 256, 0, stream>>>(xh, xl, dlist, Sb, rc);
    k_cubefin<<<NDMAX, 256, 0, stream>>>(Sb, dlist, rc);
    k_final<<<1, 1024, 0, stream>>>(rc, mnum, dd, out);
}

// Round 15
// 120.888 us; speedup vs baseline: 1.0705x; 1.0705x over previous
//
#include <hip/hip_runtime.h>
#include <math.h>

#define VV 8192
#define DD 768
#define NDMAX 256

typedef __attribute__((ext_vector_type(8))) short bf16x8;
typedef __attribute__((ext_vector_type(4))) float f32x4;

// RNE float -> bf16 bits
__device__ inline ushort f2bf(float f) {
    uint u = __float_as_uint(f);
    uint r = (u + 0x7fffu + ((u >> 16) & 1u)) >> 16;
    return (ushort)r;
}
__device__ inline float bf2f(ushort h) { return __uint_as_float(((uint)h) << 16); }

__device__ inline void gload16(const ushort* g, ushort* l) {
    __builtin_amdgcn_global_load_lds(
        (const __attribute__((address_space(1))) void*)g,
        (__attribute__((address_space(3))) void*)l, 16, 0, 0);
}

// ---------------------------------------------------------------------------
// k_normfused: per row -- L2-normalize (fp64 sumsq) -> xh/xl bf16 hi/lo
// split + norms[r]; PLUS fused column-sum partials of x = fp32(t/norm) in
// fp64. 512 blocks x 16 rows, 2-row ILP. Zeroes rc, dlist, dcount.
// ---------------------------------------------------------------------------
__global__ __launch_bounds__(256) void k_normfused(const float* __restrict__ t,
                                                   float* __restrict__ norms,
                                                   ushort* __restrict__ xh,
                                                   ushort* __restrict__ xl,
                                                   double* __restrict__ gp,
                                                   float* __restrict__ rc,
                                                   int* __restrict__ dlist,
                                                   int* __restrict__ dcount) {
    const int tid = threadIdx.x;
    const int r0 = blockIdx.x * 16;
    if (tid < 16) rc[r0 + tid] = 0.f;
    if (blockIdx.x == 0) {
        dlist[tid] = -1;
        if (tid == 0) *dcount = 0;
    }
    __shared__ double wsum[2][4];
    const int lane = tid & 63, w = tid >> 6;
    double s0 = 0.0, s1 = 0.0, s2 = 0.0;
    for (int rr = 0; rr < 16; rr += 2) {
        const float* trA = t + (size_t)(r0 + rr) * DD;
        const float* trB = trA + DD;
        float a0 = trA[tid], a1 = trA[tid + 256], a2 = trA[tid + 512];
        float b0 = trB[tid], b1 = trB[tid + 256], b2 = trB[tid + 512];
        double sA = (double)a0 * a0 + (double)a1 * a1 + (double)a2 * a2;
        double sB = (double)b0 * b0 + (double)b1 * b1 + (double)b2 * b2;
#pragma unroll
        for (int o = 32; o > 0; o >>= 1) {
            sA += __shfl_down(sA, o, 64);
            sB += __shfl_down(sB, o, 64);
        }
        if (lane == 0) { wsum[0][w] = sA; wsum[1][w] = sB; }
        __syncthreads();
        float nA = fmaxf((float)sqrt(wsum[0][0] + wsum[0][1] + wsum[0][2] + wsum[0][3]), 1e-12f);
        float nB = fmaxf((float)sqrt(wsum[1][0] + wsum[1][1] + wsum[1][2] + wsum[1][3]), 1e-12f);
        __syncthreads();  // wsum reuse protection
        if (tid == 0) {
            norms[r0 + rr] = nA;
            norms[r0 + rr + 1] = nB;
        }
        size_t baseA = (size_t)(r0 + rr) * DD, baseB = baseA + DD;
        float xA0 = a0 / nA, xA1 = a1 / nA, xA2 = a2 / nA;
        float xB0 = b0 / nB, xB1 = b1 / nB, xB2 = b2 / nB;
        ushort h;
        h = f2bf(xA0); xh[baseA + tid] = h;       xl[baseA + tid] = f2bf(xA0 - bf2f(h));
        h = f2bf(xA1); xh[baseA + tid + 256] = h; xl[baseA + tid + 256] = f2bf(xA1 - bf2f(h));
        h = f2bf(xA2); xh[baseA + tid + 512] = h; xl[baseA + tid + 512] = f2bf(xA2 - bf2f(h));
        h = f2bf(xB0); xh[baseB + tid] = h;       xl[baseB + tid] = f2bf(xB0 - bf2f(h));
        h = f2bf(xB1); xh[baseB + tid + 256] = h; xl[baseB + tid + 256] = f2bf(xB1 - bf2f(h));
        h = f2bf(xB2); xh[baseB + tid + 512] = h; xl[baseB + tid + 512] = f2bf(xB2 - bf2f(h));
        // column partials, rows in sequential order (rr then rr+1)
        s0 += (double)xA0; s0 += (double)xB0;
        s1 += (double)xA1; s1 += (double)xB1;
        s2 += (double)xA2; s2 += (double)xB2;
    }
    double* gb = gp + (size_t)blockIdx.x * DD;
    gb[tid] = s0;
    gb[tid + 256] = s1;
    gb[tid + 512] = s2;
}

// ---------------------------------------------------------------------------
// k_colsumB: g[col] = sum of 512 block partials in fixed order (fp64,
// deterministic, atomic-free).
// ---------------------------------------------------------------------------
__global__ __launch_bounds__(256) void k_colsumB(const double* __restrict__ gp,
                                                 double* __restrict__ g) {
    __shared__ double red[8][32];
    int c = threadIdx.x & 31, part = threadIdx.x >> 5;
    int col = blockIdx.x * 32 + c;
    double s = 0.0;
    for (int b = part * 64; b < part * 64 + 64; ++b)
        s += gp[(size_t)b * DD + col];
    red[part][c] = s;
    __syncthreads();
    if (part == 0) {
        double tt = 0.0;
        for (int p = 0; p < 8; ++p) tt += red[p][c];
        g[col] = tt;
    }
}

// ---------------------------------------------------------------------------
// k_mean: mnum[r] = x_r.g - x_r.x_r (fp64); dd[r] = x_r.x_r. Exact mean
// path -- numerically deadly, do not approximate. Danger-row selection
// fused (atomic compaction; slot order irrelevant).
// ---------------------------------------------------------------------------
__global__ __launch_bounds__(256) void k_mean(const float* __restrict__ t,
                                              const float* __restrict__ norms,
                                              const double* __restrict__ g,
                                              double* __restrict__ mnum,
                                              double* __restrict__ dd,
                                              int* __restrict__ dlist,
                                              int* __restrict__ dcount) {
    int r = blockIdx.x * 4 + (threadIdx.x >> 6);
    int lane = threadIdx.x & 63;
    const float* tr = t + (size_t)r * DD;
    float nrm = norms[r];
    double xg = 0.0, xx = 0.0;
#pragma unroll
    for (int k = lane; k < DD; k += 64) {
        float xf = tr[k] / nrm;
        double xv = (double)xf;
        xg += xv * g[k];
        xx += xv * xv;
    }
#pragma unroll
    for (int o = 32; o > 0; o >>= 1) {
        xg += __shfl_down(xg, o, 64);
        xx += __shfl_down(xx, o, 64);
    }
    if (lane == 0) {
        double m = xg - xx;
        mnum[r] = m;
        dd[r] = xx;
        if (fabs(m / 8191.0 + 1e-6) < 1e-5) {
            int pos = atomicAdd(dcount, 1);
            if (pos < NDMAX) dlist[pos] = r;
        }
    }
}

// ---------------------------------------------------------------------------
// k_cube: 128x256-tile bf16 MFMA pass (4 waves 2Mx2N, per-wave 64x128).
// BK=32, triple-buffered, prefetch distance 2, counted vmcnt(6) + raw
// s_barrier. LDS 72 KiB -> 2 blocks/CU. [rows][32] bf16 layout, read-slot
// swizzle li4^((l15>>1)&3) (measured conflict-free), global_load_lds w=16
// with pre-swizzled per-lane source, linear dest.
// This pass runs at ~860 TF in-flight -- the measured plateau of
// compiler-scheduled HIP for this structure class (5 independent schedule
// structures converged here); left as-is.
// Grid 1248, uniform blocks (24 K-steps):
//  - bids 0..191: strip-partial (3 seg x 2 rowpanel x 32 colchunk): danger
//    rows (gathered) x 256 cols -> store partial S into Sb (no cube).
//    Whole-panel early-exit when the rowpanel is empty (compaction is
//    contiguous).
//  - bids 192..1247: triangle tiles (hh only): 128-row x 256-col, i <= 2j+1;
//    dtile (bi>>1==bj) -> row-side only + ri==cj skip; strictly-upper adds
//    col-side by symmetry. j-major + 8x132 bijective XCD chunks.
// ---------------------------------------------------------------------------
__global__ __launch_bounds__(256, 2) void k_cube(const ushort* __restrict__ xh,
                                                 const ushort* __restrict__ xl,
                                                 const int* __restrict__ dlist,
                                                 float* __restrict__ Sb,
                                                 float* __restrict__ rc) {
    __shared__ ushort As0[4096], As1[4096], As2[4096];  // 128x32 bf16 each
    __shared__ ushort Bs0[8192], Bs1[8192], Bs2[8192];  // 256x32 bf16 each

    const int bid = blockIdx.x;
    const int tid = threadIdx.x;
    const int lane = tid & 63;
    const int wid = tid >> 6;
    const int l15 = lane & 15, li4 = lane >> 4;
    const int wm = wid >> 1, wn = wid & 1;  // 2M x 2N; per-wave 64 x 128

    const bool strip = (bid < 192);
    int bi = 0, bj = 0, seg = 0, rp = 0, cp = 0;
    if (strip) {
        seg = bid >> 6;
        int rem = bid & 63;
        rp = rem >> 5;
        cp = rem & 31;
        if (dlist[rp * 128] < 0) return;  // empty rowpanel (contiguous fill)
    } else {
        int idx = bid - 192;
        int wg = (idx & 7) * 132 + (idx >> 3);  // XCD-bijective (1056 = 8*132)
        int j = 0;
        while (wg >= 2 * j + 2) { wg -= 2 * j + 2; ++j; }  // j-major, i inner
        bi = wg;   // 0..2j+1
        bj = j;
    }
    const ushort* XA = strip ? ((seg == 1) ? xl : xh) : xh;
    const ushort* XB = strip ? ((seg == 2) ? xl : xh) : xh;

    // staging descriptors: A 2 gloads/thread, B 4 gloads/thread per K-step
    int asrc[2], bsrc[4], lda_[2], ldb_[4];
#pragma unroll
    for (int j = 0; j < 2; ++j) {
        int li = tid + j * 256;                    // 0..511
        int row = li >> 2;                         // 0..127
        int sl = ((li & 3) ^ ((li >> 3) & 3)) * 8; // pre-swizzled source slot
        int ar = strip ? dlist[rp * 128 + row] : (bi * 128 + row);
        if (ar < 0) ar = 0;
        asrc[j] = ar * DD + sl;
        lda_[j] = li * 8;
    }
#pragma unroll
    for (int j = 0; j < 4; ++j) {
        int li = tid + j * 256;                    // 0..1023
        int row = li >> 2;                         // 0..255
        int sl = ((li & 3) ^ ((li >> 3) & 3)) * 8;
        int br = strip ? (cp * 256 + row) : (bj * 256 + row);
        bsrc[j] = br * DD + sl;
        ldb_[j] = li * 8;
    }

    const int swz = (li4 ^ ((l15 >> 1) & 3)) << 3;
    const int aoff = (wm * 64 + l15) * 32 + swz;
    const int boff = (wn * 128 + l15) * 32 + swz;

    f32x4 acc[4][8];
#pragma unroll
    for (int f = 0; f < 4; ++f)
#pragma unroll
        for (int n = 0; n < 8; ++n) acc[f][n] = (f32x4){0.f, 0.f, 0.f, 0.f};

#define STG(AW, BW, KT)                                  \
    do {                                                 \
        const int kq_ = (KT) * 32;                       \
        gload16(XA + asrc[0] + kq_, (AW) + lda_[0]);     \
        gload16(XA + asrc[1] + kq_, (AW) + lda_[1]);     \
        gload16(XB + bsrc[0] + kq_, (BW) + ldb_[0]);     \
        gload16(XB + bsrc[1] + kq_, (BW) + ldb_[1]);     \
        gload16(XB + bsrc[2] + kq_, (BW) + ldb_[2]);     \
        gload16(XB + bsrc[3] + kq_, (BW) + ldb_[3]);     \
    } while (0)

#define COMPUTE(AR, BR)                                                     \
    do {                                                                    \
        bf16x8 av[4], bv[8];                                                \
        _Pragma("unroll") for (int f = 0; f < 4; ++f)                       \
            av[f] = *(const bf16x8*)((AR) + aoff + f * 512);                \
        _Pragma("unroll") for (int n = 0; n < 8; ++n)                       \
            bv[n] = *(const bf16x8*)((BR) + boff + n * 512);                \
        _Pragma("unroll") for (int f = 0; f < 4; ++f)                       \
            _Pragma("unroll") for (int n = 0; n < 8; ++n)                   \
                acc[f][n] = __builtin_amdgcn_mfma_f32_16x16x32_bf16(        \
                    av[f], bv[n], acc[f][n], 0, 0, 0);                      \
    } while (0)

#define VMW6() asm volatile("s_waitcnt vmcnt(6)" ::: "memory")
#define VMW0() asm volatile("s_waitcnt vmcnt(0)" ::: "memory")
#define RBAR() asm volatile("s_barrier" ::: "memory")

    // prologue: stage steps 0 and 1
    STG(As0, Bs0, 0);
    STG(As1, Bs1, 1);
    VMW6(); RBAR();  // step-0 loads landed

    // main loop: steps 0..20 (7 triples), each stages t+2, waits vmcnt(6)
    for (int tb = 0; tb < 21; tb += 3) {
        STG(As2, Bs2, tb + 2);
        COMPUTE(As0, Bs0);
        VMW6(); RBAR();
        STG(As0, Bs0, tb + 3);
        COMPUTE(As1, Bs1);
        VMW6(); RBAR();
        STG(As1, Bs1, tb + 4);
        COMPUTE(As2, Bs2);
        VMW6(); RBAR();
    }
    // t=21: stage 23 -> buf2; t=22, t=23 drain
    STG(As2, Bs2, 23);
    COMPUTE(As0, Bs0);
    VMW6(); RBAR();
    COMPUTE(As1, Bs1);
    VMW0(); RBAR();
    COMPUTE(As2, Bs2);
#undef STG
#undef COMPUTE
#undef VMW6
#undef VMW0
#undef RBAR

    if (strip) {
        // store partial S (f32) by danger slot; finish pass cubes later
#pragma unroll
        for (int f = 0; f < 4; ++f)
#pragma unroll
            for (int n = 0; n < 8; ++n)
#pragma unroll
                for (int r = 0; r < 4; ++r) {
                    int slot = seg * 256 + rp * 128 + wm * 64 + f * 16 + li4 * 4 + r;
                    int col = cp * 256 + wn * 128 + n * 16 + l15;
                    Sb[((size_t)slot << 13) + col] = acc[f][n][r];
                }
        return;
    }

    // triangle epilogue: cube; dtile: row-only with ri==cj skip;
    // strictly-upper: row + col (symmetry) sums.
    const bool dtile = ((bi >> 1) == bj);
    const int R0 = bi * 128, C0 = bj * 256;
    float rsum[4][4], csum[8];
#pragma unroll
    for (int n = 0; n < 8; ++n) csum[n] = 0.f;
#pragma unroll
    for (int f = 0; f < 4; ++f)
#pragma unroll
        for (int r = 0; r < 4; ++r) rsum[f][r] = 0.f;
#pragma unroll
    for (int f = 0; f < 4; ++f)
#pragma unroll
        for (int n = 0; n < 8; ++n)
#pragma unroll
            for (int r = 0; r < 4; ++r) {
                float s = acc[f][n][r];
                float c = s * s * s;
                int ri = R0 + wm * 64 + f * 16 + li4 * 4 + r;
                int cj = C0 + wn * 128 + n * 16 + l15;
                if (dtile && ri == cj) c = 0.f;
                rsum[f][r] += c;
                csum[n] += c;
            }
    // row side: reduce across the 16 col-lanes (l15)
#pragma unroll
    for (int o = 1; o < 16; o <<= 1)
#pragma unroll
        for (int f = 0; f < 4; ++f)
#pragma unroll
            for (int r = 0; r < 4; ++r)
                rsum[f][r] += __shfl_xor(rsum[f][r], o, 64);
    if (l15 == 0) {
#pragma unroll
        for (int f = 0; f < 4; ++f)
#pragma unroll
            for (int r = 0; r < 4; ++r)
                atomicAdd(&rc[R0 + wm * 64 + f * 16 + li4 * 4 + r], rsum[f][r]);
    }
    // col side (rows C0.. of S by symmetry; strictly-upper tiles only)
    if (!dtile) {
#pragma unroll
        for (int o = 16; o < 64; o <<= 1)
#pragma unroll
            for (int n = 0; n < 8; ++n) csum[n] += __shfl_xor(csum[n], o, 64);
        if (li4 == 0) {
#pragma unroll
            for (int n = 0; n < 8; ++n)
                atomicAdd(&rc[C0 + wn * 128 + n * 16 + l15], csum[n]);
        }
    }
}

// ---------------------------------------------------------------------------
// k_cubefin: per danger slot, correction = sum_c [(s0+s1+s2)^3 - s0^3]
// (skip c == drow; s0 bitwise-equals the triangle pass's hh value).
// ---------------------------------------------------------------------------
__global__ __launch_bounds__(256) void k_cubefin(const float* __restrict__ Sb,
                                                 const int* __restrict__ dlist,
                                                 float* __restrict__ rc) {
    const int slot = blockIdx.x;
    const int drow = dlist[slot];
    if (drow < 0) return;
    const int tid = threadIdx.x;
    const float* s0p = Sb + ((size_t)slot << 13);
    const float* s1p = Sb + ((size_t)(256 + slot) << 13);
    const float* s2p = Sb + ((size_t)(512 + slot) << 13);
    float sum = 0.f;
    for (int c = tid; c < VV; c += 256) {
        float s0 = s0p[c];
        float sf = s0 + s1p[c] + s2p[c];
        float d = sf * sf * sf - s0 * s0 * s0;
        if (c == drow) d = 0.f;
        sum += d;
    }
    __shared__ float red[256];
    red[tid] = sum;
    __syncthreads();
    for (int o = 128; o > 0; o >>= 1) {
        if (tid < o) red[tid] += red[tid + o];
        __syncthreads();
    }
    if (tid == 0) atomicAdd(&rc[drow], red[0]);
}

// ---------------------------------------------------------------------------
// k_final: out = collapse + 0.2 * sum_i rc_i / (mnum_i/8191 + 1e-6)
// ---------------------------------------------------------------------------
__global__ __launch_bounds__(1024) void k_final(const float* __restrict__ rc,
                                                const double* __restrict__ mnum,
                                                const double* __restrict__ dd,
                                                float* __restrict__ out) {
    int tid = threadIdx.x;
    double acc = 0.0, col = 0.0;
    for (int r = tid; r < VV; r += 1024) {
        double m = mnum[r] / 8191.0 + 1e-6;
        acc += (double)rc[r] / m;
        double dm = dd[r] - 1.0;
        col += dm * dm;
    }
    __shared__ double sa[1024], sc[1024];
    sa[tid] = acc;
    sc[tid] = col;
    __syncthreads();
    for (int o = 512; o > 0; o >>= 1) {
        if (tid < o) {
            sa[tid] += sa[tid + o];
            sc[tid] += sc[tid + o];
        }
        __syncthreads();
    }
    if (tid == 0) out[0] = (float)(sc[0] + 0.2 * sa[0]);
}

// ---------------------------------------------------------------------------
extern "C" void kernel_launch(void* const* d_in, const int* in_sizes, int n_in,
                              void* d_out, int out_size, void* d_ws, size_t ws_size,
                              hipStream_t stream) {
    const float* t = (const float*)d_in[0];
    float* out = (float*)d_out;

    char* ws = (char*)d_ws;
    float* Sb = (float*)ws;  // 3*256*8192*4B = 24 MB
    size_t off = (size_t)VV * DD * sizeof(float);  // keep 25.2 MB region
    ushort* xh = (ushort*)(ws + off); off += (size_t)VV * DD * sizeof(ushort);
    ushort* xl = (ushort*)(ws + off); off += (size_t)VV * DD * sizeof(ushort);
    double* g = (double*)(ws + off);  off += DD * sizeof(double);
    double* mnum = (double*)(ws + off); off += VV * sizeof(double);
    double* dd = (double*)(ws + off);  off += VV * sizeof(double);
    float* rc = (float*)(ws + off);    off += VV * sizeof(float);
    int* dlist = (int*)(ws + off);     off += NDMAX * sizeof(int);
    int* dcount = (int*)(ws + off);    off += sizeof(int) + 60;  // pad
    float* norms = (float*)(ws + off); off += VV * sizeof(float);
    double* gp = (double*)(ws + off);  off += (size_t)512 * DD * sizeof(double);

    k_normfused<<<512, 256, 0, stream>>>(t, norms, xh, xl, gp, rc, dlist, dcount);
    k_colsumB<<<24, 256, 0, stream>>>(gp, g);
    k_mean<<<VV / 4, 256, 0, stream>>>(t, norms, g, mnum, dd, dlist, dcount);
    k_cube<<<1248, 256, 0, stream>>>(xh, xl, dlist, Sb, rc);
    k_cubefin<<<NDMAX, 256, 0, stream>>>(Sb, dlist, rc);
    k_final<<<1, 1024, 0, stream>>>(rc, mnum, dd, out);
}